// Round 5
// baseline (398.365 us; speedup 1.0000x reference)
//
#include <hip/hip_runtime.h>
#include <hip/hip_cooperative_groups.h>
#include <math.h>

namespace cg = cooperative_groups;

#define B_    32
#define NV    32768
#define LA    64
#define DIM   128
#define OUTD  7
#define TOPK  10
#define CHUNK 2048
#define NCH   (NV / CHUNK)   // 16
#define NMW   (NV / 32)      // 1024 mask words per batch
#define MAXU  (LA * TOPK)    // 640
#define NSEG  8              // gather segments per batch
#define NBLK  256            // cooperative grid: 1 block/CU, co-resident
#define NTHR  256

// ================= fused cooperative kernel: all phases, grid-synced ============
__global__ void fused_all(const float* __restrict__ pos, const float* __restrict__ x,
                          const float* __restrict__ lig,
                          const float* __restrict__ W1, const float* __restrict__ b1,
                          const float* __restrict__ gam, const float* __restrict__ bet,
                          const float* __restrict__ rm, const float* __restrict__ rv,
                          const float* __restrict__ W2, const float* __restrict__ b2,
                          float* __restrict__ out,
                          float* __restrict__ T, unsigned int* __restrict__ cnt,
                          unsigned int* __restrict__ maskG, int* __restrict__ cand,
                          int* __restrict__ cntU, double* __restrict__ partial, int cap) {
  cg::grid_group grid = cg::this_grid();
  __shared__ float4 vp[CHUNK];  // 32 KB arena, reused across phases
  __shared__ int wtot[4], wbase[4];
  __shared__ int cntS_sh;
  const int bid = blockIdx.x, tid = threadIdx.x;
  const int w = tid >> 6, lane = tid & 63;

  // ---- phase 0: zero cnt (2048) + maskG (32768 words) --------------------------
  {
    const int total = B_ * LA + B_ * NMW;
    for (int i = bid * NTHR + tid; i < total; i += NBLK * NTHR) {
      if (i < B_ * LA) cnt[i] = 0u;
      else maskG[i - B_ * LA] = 0u;
    }
  }

  // ---- phase 1: per-(b,l) sample threshold (2 tasks per wave) ------------------
  for (int tt = 0; tt < 2; ++tt) {
    const int bl = (bid * 4 + w) * 2 + tt;      // 0..2047
    const int b = bl >> 6;
    const float lx = lig[bl * 3 + 0];
    const float ly = lig[bl * 3 + 1];
    const float lz = lig[bl * 3 + 2];
    float s[TOPK];
#pragma unroll
    for (int i = 0; i < TOPK; ++i) s[i] = INFINITY;
    const float* pb = pos + (size_t)b * NV * 3;
    for (int k = 0; k < 32; ++k) {
      int v = lane + 64 * k;
      float dx = pb[v * 3 + 0] - lx;
      float dy = pb[v * 3 + 1] - ly;
      float dz = pb[v * 3 + 2] - lz;
      float d2 = fmaf(dx, dx, fmaf(dy, dy, dz * dz));
      if (d2 < s[TOPK - 1]) {
        s[TOPK - 1] = d2;
#pragma unroll
        for (int i = TOPK - 1; i >= 1; --i)
          if (s[i] < s[i - 1]) { float t = s[i]; s[i] = s[i - 1]; s[i - 1] = t; }
      }
    }
    float T10 = 0.f;
    for (int r = 0; r < TOPK; ++r) {
      float v = s[0];
#pragma unroll
      for (int o = 1; o < 64; o <<= 1) v = fminf(v, __shfl_xor(v, o, 64));
      T10 = v;
      if (s[0] == v) {
#pragma unroll
        for (int i = 0; i < TOPK - 1; ++i) s[i] = s[i + 1];
        s[TOPK - 1] = INFINITY;
      }
    }
    if (lane == 0) T[bl] = T10;
  }
  __threadfence();
  grid.sync();

  // ---- phase 2: filter (2 chunk-tasks per block) -------------------------------
  for (int tt = 0; tt < 2; ++tt) {
    const int u = bid * 2 + tt;                 // 0..511
    const int c = u & 15, b = u >> 4;
    const int base = c * CHUNK;
    const float* pb = pos + ((size_t)b * NV + base) * 3;
    __syncthreads();  // protect vp reuse across iterations/phases
    for (int j = tid; j < CHUNK * 3; j += NTHR) {
      int v = j / 3, comp = j - 3 * v;
      float val = pb[j];
      if (comp == 0) vp[v].x = val;
      else if (comp == 1) vp[v].y = val;
      else vp[v].z = val;
    }
    __syncthreads();
    for (int v = tid; v < CHUNK; v += NTHR) {
      float px = vp[v].x, py = vp[v].y, pz = vp[v].z;
      vp[v].w = fmaf(px, px, fmaf(py, py, pz * pz));
    }
    __syncthreads();
    const int lg = tid >> 4, vl = tid & 15;
    float Ax[4], Ay[4], Az[4], TH[4];
#pragma unroll
    for (int j = 0; j < 4; ++j) {
      int l = lg + 16 * j;
      float lx = lig[(b * LA + l) * 3 + 0];
      float ly = lig[(b * LA + l) * 3 + 1];
      float lz = lig[(b * LA + l) * 3 + 2];
      Ax[j] = -2.f * lx; Ay[j] = -2.f * ly; Az[j] = -2.f * lz;
      TH[j] = T[b * LA + l] + 0.01f - (lx * lx + ly * ly + lz * lz);
    }
    for (int k = 0; k < CHUNK / 16; ++k) {
      int v = vl + 16 * k;
      float4 p = vp[v];
#pragma unroll
      for (int j = 0; j < 4; ++j) {
        float t = fmaf(p.x, Ax[j], fmaf(p.y, Ay[j], fmaf(p.z, Az[j], p.w)));
        if (t <= TH[j]) {
          int l = lg + 16 * j;
          unsigned pidx = atomicAdd(&cnt[b * LA + l], 1u);
          if (pidx < (unsigned)cap) cand[(size_t)(b * LA + l) * cap + pidx] = base + v;
        }
      }
    }
  }
  __threadfence();
  grid.sync();

  // ---- phase 3: exact top-10 over candidates + dedup bits (2 tasks/wave) -------
  for (int tt = 0; tt < 2; ++tt) {
    const int bl = (bid * 4 + w) * 2 + tt;
    const int b = bl >> 6;
    const float lx = lig[bl * 3 + 0], ly = lig[bl * 3 + 1], lz = lig[bl * 3 + 2];
    int n = (int)min(cnt[bl], (unsigned)cap);
    unsigned long long s[TOPK];
#pragma unroll
    for (int i = 0; i < TOPK; ++i) s[i] = 0xFFFFFFFFFFFFFFFFull;
    const float* pb = pos + (size_t)b * NV * 3;
    for (int i = lane; i < n; i += 64) {
      int v = cand[(size_t)bl * cap + i];
      float dx = pb[v * 3 + 0] - lx;
      float dy = pb[v * 3 + 1] - ly;
      float dz = pb[v * 3 + 2] - lz;
      float d2 = fmaf(dx, dx, fmaf(dy, dy, dz * dz));
      unsigned long long key =
          ((unsigned long long)__float_as_uint(d2) << 32) | (unsigned int)v;
      if (key < s[TOPK - 1]) {
        s[TOPK - 1] = key;
#pragma unroll
        for (int i2 = TOPK - 1; i2 >= 1; --i2)
          if (s[i2] < s[i2 - 1]) {
            unsigned long long t = s[i2]; s[i2] = s[i2 - 1]; s[i2 - 1] = t;
          }
      }
    }
    int prev = 0, myidx = 0;
    for (int r = 0; r < TOPK; ++r) {
      unsigned long long v = s[0];
#pragma unroll
      for (int o = 1; o < 64; o <<= 1) {
        unsigned long long other = __shfl_xor(v, o, 64);
        v = (other < v) ? other : v;
      }
      if (s[0] == v) {
#pragma unroll
        for (int i = 0; i < TOPK - 1; ++i) s[i] = s[i + 1];
        s[TOPK - 1] = 0xFFFFFFFFFFFFFFFFull;
      }
      int idx = (int)(unsigned int)(v & 0xFFFFFFFFu);
      if ((v >> 32) == 0xFFFFFFFFull) idx = prev;
      prev = idx;
      if (lane == r) myidx = idx;
    }
    if (lane < TOPK)
      atomicOr(&maskG[b * NMW + (myidx >> 5)], 1u << (myidx & 31));
  }
  __threadfence();
  grid.sync();

  // ---- phase 4: mask compaction + segment gather (1 seg-task per block) --------
  {
    int* list = (int*)vp;                               // 2.56 KB
    double (*red)[DIM] = (double(*)[DIM])((char*)vp + 8192);  // 2 KB @ +8KB
    const int seg = bid & 7, b = bid >> 3;
    unsigned int wd[4];
    int c = 0;
#pragma unroll
    for (int k = 0; k < 4; ++k) {
      wd[k] = maskG[b * NMW + tid * 4 + k];
      c += __popc(wd[k]);
    }
    int incl = c;
#pragma unroll
    for (int o = 1; o < 64; o <<= 1) {
      int up = __shfl_up(incl, o, 64);
      if (lane >= o) incl += up;
    }
    if (lane == 63) wtot[w] = incl;
    __syncthreads();
    if (tid == 0) {
      int s = 0;
#pragma unroll
      for (int i = 0; i < 4; ++i) { wbase[i] = s; s += wtot[i]; }
      cntS_sh = s;
    }
    __syncthreads();
    int p = wbase[w] + incl - c;
#pragma unroll
    for (int k = 0; k < 4; ++k) {
      unsigned int bits = wd[k];
      while (bits) {
        int bit = __ffs(bits) - 1;
        list[p++] = (tid * 4 + k) * 32 + bit;
        bits &= bits - 1;
      }
    }
    __syncthreads();
    const int n = cntS_sh;
    if (seg == 0 && tid == 0) cntU[b] = n;
    const int r0 = (seg * n) / NSEG, r1 = ((seg + 1) * n) / NSEG;
    const int slot = tid >> 7, col = tid & 127;
    const float* xb = x + (size_t)b * NV * DIM;
    double a0 = 0, a1 = 0, a2 = 0, a3 = 0;
    int i = r0 + slot;
    for (; i + 6 < r1; i += 8) {
      float v0 = xb[(size_t)list[i + 0] * DIM + col];
      float v1 = xb[(size_t)list[i + 2] * DIM + col];
      float v2 = xb[(size_t)list[i + 4] * DIM + col];
      float v3 = xb[(size_t)list[i + 6] * DIM + col];
      a0 += (double)v0; a1 += (double)v1; a2 += (double)v2; a3 += (double)v3;
    }
    for (; i < r1; i += 2) a0 += (double)xb[(size_t)list[i] * DIM + col];
    red[slot][col] = ((a0 + a1) + (a2 + a3));
    __syncthreads();
    if (tid < DIM)
      partial[((size_t)b * NSEG + seg) * DIM + tid] = red[0][tid] + red[1][tid];
  }
  __threadfence();
  grid.sync();

  // ---- phase 5: reduce partials + top_net MLP (blocks 0..31) -------------------
  if (bid < B_) {
    float* embS = (float*)vp;
    float* hS = embS + DIM;
    const int b = bid, d = tid;
    if (d < DIM) {
      double s = 0;
#pragma unroll
      for (int seg = 0; seg < NSEG; ++seg)
        s += partial[((size_t)b * NSEG + seg) * DIM + d];
      embS[d] = (float)(s / (double)cntU[b]);
    }
    __syncthreads();
    if (d < DIM) {
      float h = b1[d];
      for (int dd = 0; dd < DIM; ++dd) h = fmaf(embS[dd], W1[dd * DIM + d], h);
      h = (h - rm[d]) / sqrtf(rv[d] + 1e-5f) * gam[d] + bet[d];
      h = h / (1.f + expf(-h));
      hS[d] = h;
    }
    __syncthreads();
    if (d < OUTD) {
      float o = b2[d];
      for (int dd = 0; dd < DIM; ++dd) o = fmaf(hS[dd], W2[dd * OUTD + d], o);
      out[b * OUTD + d] = o;
    }
  }
}

// ================= fallback path: the proven 5-kernel pipeline ==================
__global__ void k1_threshold(const float* __restrict__ pos, const float* __restrict__ lig,
                             float* __restrict__ T, unsigned int* __restrict__ cnt,
                             unsigned int* __restrict__ maskG) {
  const int l = blockIdx.x, b = blockIdx.y;
  const int lane = threadIdx.x;
  const int bl = b * LA + l;
  if (lane == 0) cnt[bl] = 0u;
  if (lane < 16) maskG[b * NMW + l * 16 + lane] = 0u;
  const float lx = lig[bl * 3 + 0];
  const float ly = lig[bl * 3 + 1];
  const float lz = lig[bl * 3 + 2];
  float s[TOPK];
#pragma unroll
  for (int i = 0; i < TOPK; ++i) s[i] = INFINITY;
  const float* pb = pos + (size_t)b * NV * 3;
  for (int k = 0; k < 32; ++k) {
    int v = lane + 64 * k;
    float dx = pb[v * 3 + 0] - lx;
    float dy = pb[v * 3 + 1] - ly;
    float dz = pb[v * 3 + 2] - lz;
    float d2 = fmaf(dx, dx, fmaf(dy, dy, dz * dz));
    if (d2 < s[TOPK - 1]) {
      s[TOPK - 1] = d2;
#pragma unroll
      for (int i = TOPK - 1; i >= 1; --i)
        if (s[i] < s[i - 1]) { float t = s[i]; s[i] = s[i - 1]; s[i - 1] = t; }
    }
  }
  float T10 = 0.f;
  for (int r = 0; r < TOPK; ++r) {
    float v = s[0];
#pragma unroll
    for (int o = 1; o < 64; o <<= 1) v = fminf(v, __shfl_xor(v, o, 64));
    T10 = v;
    if (s[0] == v) {
#pragma unroll
      for (int i = 0; i < TOPK - 1; ++i) s[i] = s[i + 1];
      s[TOPK - 1] = INFINITY;
    }
  }
  if (lane == 0) T[bl] = T10;
}

__global__ void k2_filter(const float* __restrict__ pos, const float* __restrict__ lig,
                          const float* __restrict__ T, unsigned int* __restrict__ cnt,
                          int* __restrict__ cand, int cap) {
  __shared__ float4 vp[CHUNK];
  const int c = blockIdx.x, b = blockIdx.y;
  const int tid = threadIdx.x;
  const int base = c * CHUNK;
  const float* pb = pos + ((size_t)b * NV + base) * 3;
  for (int j = tid; j < CHUNK * 3; j += 256) {
    int v = j / 3, comp = j - 3 * v;
    float val = pb[j];
    if (comp == 0) vp[v].x = val;
    else if (comp == 1) vp[v].y = val;
    else vp[v].z = val;
  }
  __syncthreads();
  for (int v = tid; v < CHUNK; v += 256) {
    float px = vp[v].x, py = vp[v].y, pz = vp[v].z;
    vp[v].w = fmaf(px, px, fmaf(py, py, pz * pz));
  }
  __syncthreads();
  const int lg = tid >> 4, vl = tid & 15;
  float Ax[4], Ay[4], Az[4], TH[4];
#pragma unroll
  for (int j = 0; j < 4; ++j) {
    int l = lg + 16 * j;
    float lx = lig[(b * LA + l) * 3 + 0];
    float ly = lig[(b * LA + l) * 3 + 1];
    float lz = lig[(b * LA + l) * 3 + 2];
    Ax[j] = -2.f * lx; Ay[j] = -2.f * ly; Az[j] = -2.f * lz;
    TH[j] = T[b * LA + l] + 0.01f - (lx * lx + ly * ly + lz * lz);
  }
  for (int k = 0; k < CHUNK / 16; ++k) {
    int v = vl + 16 * k;
    float4 p = vp[v];
#pragma unroll
    for (int j = 0; j < 4; ++j) {
      float t = fmaf(p.x, Ax[j], fmaf(p.y, Ay[j], fmaf(p.z, Az[j], p.w)));
      if (t <= TH[j]) {
        int l = lg + 16 * j;
        unsigned pidx = atomicAdd(&cnt[b * LA + l], 1u);
        if (pidx < (unsigned)cap) cand[(size_t)(b * LA + l) * cap + pidx] = base + v;
      }
    }
  }
}

__global__ void k3_select(const float* __restrict__ pos, const float* __restrict__ lig,
                          const unsigned int* __restrict__ cnt,
                          const int* __restrict__ cand, int cap,
                          unsigned int* __restrict__ maskG) {
  const int bl = blockIdx.x;
  const int b = bl / LA;
  const int lane = threadIdx.x;
  const float lx = lig[bl * 3 + 0], ly = lig[bl * 3 + 1], lz = lig[bl * 3 + 2];
  int n = (int)min(cnt[bl], (unsigned)cap);
  unsigned long long s[TOPK];
#pragma unroll
  for (int i = 0; i < TOPK; ++i) s[i] = 0xFFFFFFFFFFFFFFFFull;
  const float* pb = pos + (size_t)b * NV * 3;
  for (int i = lane; i < n; i += 64) {
    int v = cand[(size_t)bl * cap + i];
    float dx = pb[v * 3 + 0] - lx;
    float dy = pb[v * 3 + 1] - ly;
    float dz = pb[v * 3 + 2] - lz;
    float d2 = fmaf(dx, dx, fmaf(dy, dy, dz * dz));
    unsigned long long key =
        ((unsigned long long)__float_as_uint(d2) << 32) | (unsigned int)v;
    if (key < s[TOPK - 1]) {
      s[TOPK - 1] = key;
#pragma unroll
      for (int i2 = TOPK - 1; i2 >= 1; --i2)
        if (s[i2] < s[i2 - 1]) {
          unsigned long long t = s[i2]; s[i2] = s[i2 - 1]; s[i2 - 1] = t;
        }
    }
  }
  int prev = 0, myidx = 0;
  for (int r = 0; r < TOPK; ++r) {
    unsigned long long v = s[0];
#pragma unroll
    for (int o = 1; o < 64; o <<= 1) {
      unsigned long long other = __shfl_xor(v, o, 64);
      v = (other < v) ? other : v;
    }
    if (s[0] == v) {
#pragma unroll
      for (int i = 0; i < TOPK - 1; ++i) s[i] = s[i + 1];
      s[TOPK - 1] = 0xFFFFFFFFFFFFFFFFull;
    }
    int idx = (int)(unsigned int)(v & 0xFFFFFFFFu);
    if ((v >> 32) == 0xFFFFFFFFull) idx = prev;
    prev = idx;
    if (lane == r) myidx = idx;
  }
  if (lane < TOPK)
    atomicOr(&maskG[b * NMW + (myidx >> 5)], 1u << (myidx & 31));
}

__global__ void k4a_gather(const float* __restrict__ x, const unsigned int* __restrict__ maskG,
                           int* __restrict__ cntU, double* __restrict__ partial) {
  __shared__ int list[MAXU];
  __shared__ int wtot[4], wbase[4];
  __shared__ int cntS;
  __shared__ double red[2][DIM];
  const int seg = blockIdx.x, b = blockIdx.y, tid = threadIdx.x;
  const int w = tid >> 6, lane = tid & 63;
  unsigned int wd[4];
  int c = 0;
#pragma unroll
  for (int k = 0; k < 4; ++k) {
    wd[k] = maskG[b * NMW + tid * 4 + k];
    c += __popc(wd[k]);
  }
  int incl = c;
#pragma unroll
  for (int o = 1; o < 64; o <<= 1) {
    int up = __shfl_up(incl, o, 64);
    if (lane >= o) incl += up;
  }
  if (lane == 63) wtot[w] = incl;
  __syncthreads();
  if (tid == 0) {
    int s = 0;
#pragma unroll
    for (int i = 0; i < 4; ++i) { wbase[i] = s; s += wtot[i]; }
    cntS = s;
  }
  __syncthreads();
  int p = wbase[w] + incl - c;
#pragma unroll
  for (int k = 0; k < 4; ++k) {
    unsigned int bits = wd[k];
    while (bits) {
      int bit = __ffs(bits) - 1;
      list[p++] = (tid * 4 + k) * 32 + bit;
      bits &= bits - 1;
    }
  }
  __syncthreads();
  const int n = cntS;
  if (seg == 0 && tid == 0) cntU[b] = n;
  const int r0 = (seg * n) / NSEG, r1 = ((seg + 1) * n) / NSEG;
  const int slot = tid >> 7, col = tid & 127;
  const float* xb = x + (size_t)b * NV * DIM;
  double a0 = 0, a1 = 0, a2 = 0, a3 = 0;
  int i = r0 + slot;
  for (; i + 6 < r1; i += 8) {
    float v0 = xb[(size_t)list[i + 0] * DIM + col];
    float v1 = xb[(size_t)list[i + 2] * DIM + col];
    float v2 = xb[(size_t)list[i + 4] * DIM + col];
    float v3 = xb[(size_t)list[i + 6] * DIM + col];
    a0 += (double)v0; a1 += (double)v1; a2 += (double)v2; a3 += (double)v3;
  }
  for (; i < r1; i += 2) a0 += (double)xb[(size_t)list[i] * DIM + col];
  red[slot][col] = ((a0 + a1) + (a2 + a3));
  __syncthreads();
  if (tid < DIM)
    partial[((size_t)b * NSEG + seg) * DIM + tid] = red[0][tid] + red[1][tid];
}

__global__ void k4b_mlp(const double* __restrict__ partial, const int* __restrict__ cntU,
                        const float* __restrict__ W1, const float* __restrict__ b1,
                        const float* __restrict__ gamma, const float* __restrict__ beta,
                        const float* __restrict__ rm, const float* __restrict__ rv,
                        const float* __restrict__ W2, const float* __restrict__ b2,
                        float* __restrict__ out) {
  __shared__ float embS[DIM];
  __shared__ float hS[DIM];
  const int b = blockIdx.x, d = threadIdx.x;
  double s = 0;
#pragma unroll
  for (int seg = 0; seg < NSEG; ++seg)
    s += partial[((size_t)b * NSEG + seg) * DIM + d];
  embS[d] = (float)(s / (double)cntU[b]);
  __syncthreads();
  float h = b1[d];
  for (int dd = 0; dd < DIM; ++dd) h = fmaf(embS[dd], W1[dd * DIM + d], h);
  h = (h - rm[d]) / sqrtf(rv[d] + 1e-5f) * gamma[d] + beta[d];
  h = h / (1.f + expf(-h));
  hS[d] = h;
  __syncthreads();
  if (d < OUTD) {
    float o = b2[d];
    for (int dd = 0; dd < DIM; ++dd) o = fmaf(hS[dd], W2[dd * OUTD + d], o);
    out[b * OUTD + d] = o;
  }
}

extern "C" void kernel_launch(void* const* d_in, const int* in_sizes, int n_in,
                              void* d_out, int out_size, void* d_ws, size_t ws_size,
                              hipStream_t stream) {
  const float* pos  = (const float*)d_in[0];
  const float* x    = (const float*)d_in[1];
  const float* lig  = (const float*)d_in[2];
  const float* W1   = (const float*)d_in[3];
  const float* b1   = (const float*)d_in[4];
  const float* gam  = (const float*)d_in[5];
  const float* bet  = (const float*)d_in[6];
  const float* rm   = (const float*)d_in[7];
  const float* rv   = (const float*)d_in[8];
  const float* W2   = (const float*)d_in[9];
  const float* b2   = (const float*)d_in[10];
  float* out = (float*)d_out;

  char* ws = (char*)d_ws;
  const int NBL = B_ * LA;  // 2048
  float* T            = (float*)(ws);                     // 8 KB
  unsigned int* cnt   = (unsigned int*)(ws + 8192);       // 8 KB
  unsigned int* maskG = (unsigned int*)(ws + 16384);      // 128 KB
  int* cntU           = (int*)(ws + 147456);              // 128 B
  double* partial     = (double*)(ws + 147584);           // 256 KB
  int* cand           = (int*)(ws + 409728);
  size_t fixed = 409728;
  size_t avail = ws_size > fixed ? ws_size - fixed : 0;
  int cap = (int)(avail / ((size_t)NBL * 4));
  if (cap > 1024) cap = 1024;
  if (cap < 16) cap = 16;

  void* args[] = {(void*)&pos, (void*)&x, (void*)&lig, (void*)&W1, (void*)&b1,
                  (void*)&gam, (void*)&bet, (void*)&rm, (void*)&rv, (void*)&W2,
                  (void*)&b2, (void*)&out, (void*)&T, (void*)&cnt, (void*)&maskG,
                  (void*)&cand, (void*)&cntU, (void*)&partial, (void*)&cap};
  hipError_t e = hipLaunchCooperativeKernel((const void*)fused_all, dim3(NBLK),
                                            dim3(NTHR), args, 0, stream);
  if (e != hipSuccess) {
    // fallback: proven 5-kernel pipeline (identical math)
    k1_threshold<<<dim3(LA, B_), 64, 0, stream>>>(pos, lig, T, cnt, maskG);
    k2_filter<<<dim3(NCH, B_), 256, 0, stream>>>(pos, lig, T, cnt, cand, cap);
    k3_select<<<NBL, 64, 0, stream>>>(pos, lig, cnt, cand, cap, maskG);
    k4a_gather<<<dim3(NSEG, B_), 256, 0, stream>>>(x, maskG, cntU, partial);
    k4b_mlp<<<B_, 128, 0, stream>>>(partial, cntU, W1, b1, gam, bet, rm, rv, W2, b2, out);
  }
}

// Round 6
// 112.671 us; speedup vs baseline: 3.5356x; 3.5356x over previous
//
#include <hip/hip_runtime.h>
#include <math.h>

#define B_    32
#define NV    32768
#define LA    64
#define DIM   128
#define OUTD  7
#define TOPK  10
#define CHUNK 1024
#define NCH   (NV / CHUNK)   // 32
#define NMW   (NV / 32)      // 1024 mask words per batch
#define MAXU  (LA * TOPK)    // 640
#define NSEG  16             // gather segments per batch

// ---------------- K1: per-(b,l) sample threshold, 4 waves/task ------------------
// grid (LA, B_), block 256. Each wave samples 512 contiguous vertices (8 iters),
// computes wave top-10, then wave 0 merges 40 keys -> T (upper bound on 10th-NN).
__global__ void k1_threshold(const float* __restrict__ pos,
                             const float* __restrict__ lig,
                             float* __restrict__ T, unsigned int* __restrict__ cnt,
                             unsigned int* __restrict__ maskG) {
  __shared__ float m[4 * TOPK];
  const int l = blockIdx.x, b = blockIdx.y;
  const int tid = threadIdx.x, w = tid >> 6, lane = tid & 63;
  const int bl = b * LA + l;
  if (tid == 0) cnt[bl] = 0u;
  if (tid < 16) maskG[b * NMW + l * 16 + tid] = 0u;
  const float lx = lig[bl * 3 + 0];
  const float ly = lig[bl * 3 + 1];
  const float lz = lig[bl * 3 + 2];
  float s[TOPK];
#pragma unroll
  for (int i = 0; i < TOPK; ++i) s[i] = INFINITY;
  const float* pb = pos + (size_t)b * NV * 3;
#pragma unroll
  for (int k = 0; k < 8; ++k) {
    int v = w * 512 + lane + 64 * k;
    float dx = pb[v * 3 + 0] - lx;
    float dy = pb[v * 3 + 1] - ly;
    float dz = pb[v * 3 + 2] - lz;
    float d2 = fmaf(dx, dx, fmaf(dy, dy, dz * dz));
    if (d2 < s[TOPK - 1]) {
      s[TOPK - 1] = d2;
#pragma unroll
      for (int i = TOPK - 1; i >= 1; --i)
        if (s[i] < s[i - 1]) { float t = s[i]; s[i] = s[i - 1]; s[i - 1] = t; }
    }
  }
  // wave top-10 via 10 rounds of min+consume (dup-consume only enlarges T: safe)
  for (int r = 0; r < TOPK; ++r) {
    float v = s[0];
#pragma unroll
    for (int o = 1; o < 64; o <<= 1) v = fminf(v, __shfl_xor(v, o, 64));
    if (s[0] == v) {
#pragma unroll
      for (int i = 0; i < TOPK - 1; ++i) s[i] = s[i + 1];
      s[TOPK - 1] = INFINITY;
    }
    if (lane == r) m[w * TOPK + r] = v;
  }
  __syncthreads();
  if (w == 0) {
    float val = (lane < 4 * TOPK) ? m[lane] : INFINITY;
    float T10 = 0.f;
    for (int r = 0; r < TOPK; ++r) {
      float v = val;
#pragma unroll
      for (int o = 1; o < 64; o <<= 1) v = fminf(v, __shfl_xor(v, o, 64));
      T10 = v;
      if (val == v) val = INFINITY;  // consume (ties consumed together: T grows, safe)
    }
    if (lane == 0) T[bl] = T10;
  }
}

// ---------------- K2: filter pass -- append candidates with d2 <= T + slack ----
// grid (NCH, B_) = 1024 blocks, block 256, 16 KB LDS -> 4 blocks/CU.
__global__ void k2_filter(const float* __restrict__ pos,
                          const float* __restrict__ lig,
                          const float* __restrict__ T,
                          unsigned int* __restrict__ cnt,
                          int* __restrict__ cand, int cap) {
  __shared__ float4 vp[CHUNK];  // 16 KB
  const int c = blockIdx.x, b = blockIdx.y;
  const int tid = threadIdx.x;
  const int base = c * CHUNK;
  const float* pb = pos + ((size_t)b * NV + base) * 3;
  for (int j = tid; j < CHUNK * 3; j += 256) {
    int v = j / 3, comp = j - 3 * v;
    float val = pb[j];
    if (comp == 0) vp[v].x = val;
    else if (comp == 1) vp[v].y = val;
    else vp[v].z = val;
  }
  __syncthreads();
  for (int v = tid; v < CHUNK; v += 256) {
    float px = vp[v].x, py = vp[v].y, pz = vp[v].z;
    vp[v].w = fmaf(px, px, fmaf(py, py, pz * pz));
  }
  __syncthreads();
  const int lg = tid >> 4, vl = tid & 15;
  float Ax[4], Ay[4], Az[4], TH[4];
#pragma unroll
  for (int j = 0; j < 4; ++j) {
    int l = lg + 16 * j;
    float lx = lig[(b * LA + l) * 3 + 0];
    float ly = lig[(b * LA + l) * 3 + 1];
    float lz = lig[(b * LA + l) * 3 + 2];
    Ax[j] = -2.f * lx; Ay[j] = -2.f * ly; Az[j] = -2.f * lz;
    TH[j] = T[b * LA + l] + 0.01f - (lx * lx + ly * ly + lz * lz);
  }
  for (int k = 0; k < CHUNK / 16; ++k) {
    int v = vl + 16 * k;
    float4 p = vp[v];
#pragma unroll
    for (int j = 0; j < 4; ++j) {
      float t = fmaf(p.x, Ax[j], fmaf(p.y, Ay[j], fmaf(p.z, Az[j], p.w)));
      if (t <= TH[j]) {
        int l = lg + 16 * j;
        unsigned pidx = atomicAdd(&cnt[b * LA + l], 1u);
        if (pidx < (unsigned)cap) cand[(size_t)(b * LA + l) * cap + pidx] = base + v;
      }
    }
  }
}

// ---------------- K3: exact top-10 over candidates, 4 waves/task ----------------
// grid 2048, block 256. Per-wave top-10 over a strided quarter, exact LDS merge
// (u64 keys unique per vertex), winners set dedup bits.
__global__ void k3_select(const float* __restrict__ pos,
                          const float* __restrict__ lig,
                          const unsigned int* __restrict__ cnt,
                          const int* __restrict__ cand, int cap,
                          unsigned int* __restrict__ maskG) {
  __shared__ unsigned long long kk[4 * TOPK];
  const int bl = blockIdx.x;
  const int b = bl / LA;
  const int tid = threadIdx.x, w = tid >> 6, lane = tid & 63;
  const float lx = lig[bl * 3 + 0], ly = lig[bl * 3 + 1], lz = lig[bl * 3 + 2];
  int n = (int)min(cnt[bl], (unsigned)cap);
  unsigned long long s[TOPK];
#pragma unroll
  for (int i = 0; i < TOPK; ++i) s[i] = 0xFFFFFFFFFFFFFFFFull;
  const float* pb = pos + (size_t)b * NV * 3;
  for (int i = w * 64 + lane; i < n; i += 256) {
    int v = cand[(size_t)bl * cap + i];
    float dx = pb[v * 3 + 0] - lx;
    float dy = pb[v * 3 + 1] - ly;
    float dz = pb[v * 3 + 2] - lz;
    float d2 = fmaf(dx, dx, fmaf(dy, dy, dz * dz));
    unsigned long long key =
        ((unsigned long long)__float_as_uint(d2) << 32) | (unsigned int)v;
    if (key < s[TOPK - 1]) {
      s[TOPK - 1] = key;
#pragma unroll
      for (int i2 = TOPK - 1; i2 >= 1; --i2)
        if (s[i2] < s[i2 - 1]) {
          unsigned long long t = s[i2]; s[i2] = s[i2 - 1]; s[i2 - 1] = t;
        }
    }
  }
  for (int r = 0; r < TOPK; ++r) {
    unsigned long long v = s[0];
#pragma unroll
    for (int o = 1; o < 64; o <<= 1) {
      unsigned long long other = __shfl_xor(v, o, 64);
      v = (other < v) ? other : v;
    }
    if (s[0] == v) {
#pragma unroll
      for (int i = 0; i < TOPK - 1; ++i) s[i] = s[i + 1];
      s[TOPK - 1] = 0xFFFFFFFFFFFFFFFFull;
    }
    if (lane == r) kk[w * TOPK + r] = v;
  }
  __syncthreads();
  if (w == 0) {
    unsigned long long key = (lane < 4 * TOPK) ? kk[lane] : 0xFFFFFFFFFFFFFFFFull;
    int prev = 0, myidx = 0;
    for (int r = 0; r < TOPK; ++r) {
      unsigned long long v = key;
#pragma unroll
      for (int o = 1; o < 64; o <<= 1) {
        unsigned long long other = __shfl_xor(v, o, 64);
        v = (other < v) ? other : v;
      }
      if (key == v) key = 0xFFFFFFFFFFFFFFFFull;  // keys unique: exact consume
      int idx = (int)(unsigned int)(v & 0xFFFFFFFFu);
      if ((v >> 32) == 0xFFFFFFFFull) idx = prev;  // pad guard
      prev = idx;
      if (lane == r) myidx = idx;
    }
    if (lane < TOPK)
      atomicOr(&maskG[b * NMW + (myidx >> 5)], 1u << (myidx & 31));
  }
}

// ---------------- K4a: mask compaction + segment gather (f64, deterministic) ----
// grid (NSEG, B_) = 512 blocks, block 256.
__global__ void k4a_gather(const float* __restrict__ x,
                           const unsigned int* __restrict__ maskG,
                           int* __restrict__ cntU,
                           double* __restrict__ partial) {
  __shared__ int list[MAXU];     // 2.56 KB
  __shared__ int wtot[4], wbase[4];
  __shared__ int cntS;
  __shared__ double red[2][DIM]; // 2 KB
  const int seg = blockIdx.x, b = blockIdx.y, tid = threadIdx.x;
  const int w = tid >> 6, lane = tid & 63;
  unsigned int wd[4];
  int c = 0;
#pragma unroll
  for (int k = 0; k < 4; ++k) {
    wd[k] = maskG[b * NMW + tid * 4 + k];
    c += __popc(wd[k]);
  }
  int incl = c;
#pragma unroll
  for (int o = 1; o < 64; o <<= 1) {
    int up = __shfl_up(incl, o, 64);
    if (lane >= o) incl += up;
  }
  if (lane == 63) wtot[w] = incl;
  __syncthreads();
  if (tid == 0) {
    int s = 0;
#pragma unroll
    for (int i = 0; i < 4; ++i) { wbase[i] = s; s += wtot[i]; }
    cntS = s;
  }
  __syncthreads();
  int p = wbase[w] + incl - c;
#pragma unroll
  for (int k = 0; k < 4; ++k) {
    unsigned int bits = wd[k];
    while (bits) {
      int bit = __ffs(bits) - 1;
      list[p++] = (tid * 4 + k) * 32 + bit;
      bits &= bits - 1;
    }
  }
  __syncthreads();
  const int n = cntS;
  if (seg == 0 && tid == 0) cntU[b] = n;
  const int r0 = (seg * n) / NSEG, r1 = ((seg + 1) * n) / NSEG;
  const int slot = tid >> 7, col = tid & 127;
  const float* xb = x + (size_t)b * NV * DIM;
  double a0 = 0, a1 = 0, a2 = 0, a3 = 0;
  int i = r0 + slot;
  for (; i + 6 < r1; i += 8) {
    float v0 = xb[(size_t)list[i + 0] * DIM + col];
    float v1 = xb[(size_t)list[i + 2] * DIM + col];
    float v2 = xb[(size_t)list[i + 4] * DIM + col];
    float v3 = xb[(size_t)list[i + 6] * DIM + col];
    a0 += (double)v0; a1 += (double)v1; a2 += (double)v2; a3 += (double)v3;
  }
  for (; i < r1; i += 2) a0 += (double)xb[(size_t)list[i] * DIM + col];
  red[slot][col] = ((a0 + a1) + (a2 + a3));
  __syncthreads();
  if (tid < DIM)
    partial[((size_t)b * NSEG + seg) * DIM + tid] = red[0][tid] + red[1][tid];
}

// ---------------- K4b: reduce partials + top_net MLP (split dot products) -------
// grid B_, block 256.
__global__ void k4b_mlp(const double* __restrict__ partial,
                        const int* __restrict__ cntU,
                        const float* __restrict__ W1, const float* __restrict__ b1,
                        const float* __restrict__ gamma, const float* __restrict__ beta,
                        const float* __restrict__ rm, const float* __restrict__ rv,
                        const float* __restrict__ W2, const float* __restrict__ b2,
                        float* __restrict__ out) {
  __shared__ float embS[DIM];
  __shared__ float hpart[2][DIM];
  __shared__ float hS[DIM];
  const int b = blockIdx.x, t = threadIdx.x;
  if (t < DIM) {
    double s = 0;
#pragma unroll
    for (int seg = 0; seg < NSEG; ++seg)
      s += partial[((size_t)b * NSEG + seg) * DIM + t];
    embS[t] = (float)(s / (double)cntU[b]);
  }
  __syncthreads();
  {
    const int d = t & 127, half = t >> 7;
    float hp = 0.f;
    const int dd0 = half * 64;
#pragma unroll 8
    for (int dd = dd0; dd < dd0 + 64; ++dd) hp = fmaf(embS[dd], W1[dd * DIM + d], hp);
    hpart[half][d] = hp;
  }
  __syncthreads();
  if (t < DIM) {
    float h = hpart[0][t] + hpart[1][t] + b1[t];
    h = (h - rm[t]) / sqrtf(rv[t] + 1e-5f) * gamma[t] + beta[t];
    h = h / (1.f + expf(-h));
    hS[t] = h;
  }
  __syncthreads();
  if (t < OUTD * 16) {
    const int o = t >> 4, g = t & 15;
    float p = 0.f;
#pragma unroll
    for (int dd = g * 8; dd < g * 8 + 8; ++dd) p = fmaf(hS[dd], W2[dd * OUTD + o], p);
#pragma unroll
    for (int off = 8; off >= 1; off >>= 1) p += __shfl_down(p, off, 16);
    if (g == 0) out[b * OUTD + o] = p + b2[o];
  }
}

extern "C" void kernel_launch(void* const* d_in, const int* in_sizes, int n_in,
                              void* d_out, int out_size, void* d_ws, size_t ws_size,
                              hipStream_t stream) {
  const float* pos  = (const float*)d_in[0];
  const float* x    = (const float*)d_in[1];
  const float* lig  = (const float*)d_in[2];
  const float* W1   = (const float*)d_in[3];
  const float* b1   = (const float*)d_in[4];
  const float* gam  = (const float*)d_in[5];
  const float* bet  = (const float*)d_in[6];
  const float* rm   = (const float*)d_in[7];
  const float* rv   = (const float*)d_in[8];
  const float* W2   = (const float*)d_in[9];
  const float* b2   = (const float*)d_in[10];
  float* out = (float*)d_out;

  // workspace carve-up
  char* ws = (char*)d_ws;
  const int NBL = B_ * LA;  // 2048
  float* T            = (float*)(ws);                     // 8 KB
  unsigned int* cnt   = (unsigned int*)(ws + 8192);       // 8 KB
  unsigned int* maskG = (unsigned int*)(ws + 16384);      // 128 KB
  int* cntU           = (int*)(ws + 147456);              // 128 B
  double* partial     = (double*)(ws + 147584);           // 512 KB (32*16*128*8)
  int* cand           = (int*)(ws + 671872);
  size_t fixed = 671872;
  size_t avail = ws_size > fixed ? ws_size - fixed : 0;
  int cap = (int)(avail / ((size_t)NBL * 4));
  if (cap > 1024) cap = 1024;
  if (cap < 16) cap = 16;

  k1_threshold<<<dim3(LA, B_), 256, 0, stream>>>(pos, lig, T, cnt, maskG);
  k2_filter<<<dim3(NCH, B_), 256, 0, stream>>>(pos, lig, T, cnt, cand, cap);
  k3_select<<<NBL, 256, 0, stream>>>(pos, lig, cnt, cand, cap, maskG);
  k4a_gather<<<dim3(NSEG, B_), 256, 0, stream>>>(x, maskG, cntU, partial);
  k4b_mlp<<<B_, 256, 0, stream>>>(partial, cntU, W1, b1, gam, bet, rm, rv, W2, b2, out);
}